// Round 6
// baseline (1598.190 us; speedup 1.0000x reference)
//
#include <hip/hip_runtime.h>

// Instant-NGP 2D hashgrid (L=16, T=2^20, F=2, N_MIN=16, b=2) + MLP 32->128->128->3.
// R6: dur = FETCH/3.47TB/s held for 5 rounds -> minimize L2-miss bytes.
//  K1 cvt: hashed tables (lvl 6..15) f32 -> bf16 (4MB/level = one XCD L2).
//  K2 encode: per-level atomic chunk queues; blocks read their REAL XCD id via
//     s_getreg(HW_REG_XCC_ID) [HW-verified m09], drain their own levels first,
//     then work-steal (correct under ANY block->XCD mapping). uv loads and
//     feats stores are non-temporal so streams don't evict the hot table.
//  K3 mlp: MFMA MLP with ALL weights in LDS fragments (no per-thread weight
//     arrays -> nothing the allocator can demote to scratch), nt feats loads.
// mfma_f32_16x16x32_bf16 layouts (HW-verified):
//   A[m][k]: m=lane&15, k=(lane>>4)*8+j   B[k][n]: n=lane&15, k=(lane>>4)*8+j
//   D[m][n]: n=lane&15, m=(lane>>4)*4+r
// Lane (quad,lo) consumes levels 4q..4q+3 of point lo == its B-fragment.

#define T_SIZE  (1u << 20)
#define HASH_Y  2654435761u
#define NLVL    16
#define CHPTS   512                     // points per queue chunk (one wave)

typedef __bf16 bf16x8 __attribute__((ext_vector_type(8)));
typedef float f32x4 __attribute__((ext_vector_type(4)));
typedef unsigned short u16x8 __attribute__((ext_vector_type(8)));
typedef unsigned short u16x4 __attribute__((ext_vector_type(4)));
typedef unsigned int uint32;

static __device__ __forceinline__ unsigned short f2bf(float f) {
    union { float f; unsigned u; } v; v.f = f;
    unsigned u = v.u;
    u += 0x7fffu + ((u >> 16) & 1u);   // RNE
    return (unsigned short)(u >> 16);
}
static __device__ __forceinline__ uint32 pack2(float a, float b) {
    return (uint32)f2bf(a) | ((uint32)f2bf(b) << 16);
}
static __device__ __forceinline__ float bflo(uint32 u) {
    union { unsigned u; float f; } v; v.u = u << 16; return v.f;
}
static __device__ __forceinline__ float bfhi(uint32 u) {
    union { unsigned u; float f; } v; v.u = u & 0xffff0000u; return v.f;
}
static __device__ __forceinline__ float bfu(unsigned short s) {
    union { unsigned u; float f; } v; v.u = (unsigned)s << 16; return v.f;
}
static __device__ __forceinline__ f32x4 mfma16(u16x8 a, u16x8 b, f32x4 c) {
    return __builtin_amdgcn_mfma_f32_16x16x32_bf16(
        __builtin_bit_cast(bf16x8, a), __builtin_bit_cast(bf16x8, b), c, 0, 0, 0);
}

// ---------------- K1: hashed tables f32 -> packed bf16 ----------------
__global__ __launch_bounds__(256, 8)
void cvt_tables(const float4* __restrict__ in, uint2* __restrict__ out, int n4) {
    int stride = gridDim.x * blockDim.x;
    for (int i = blockIdx.x * blockDim.x + threadIdx.x; i < n4; i += stride) {
        float4 f = in[i];
        uint2 o;
        o.x = pack2(f.x, f.y);
        o.y = pack2(f.z, f.w);
        out[i] = o;
    }
}

// ---------------- K2: queue-driven per-level encode ----------------
// One wave pulls one CHPTS-point chunk of one level at a time.
static __device__ __forceinline__ void run_level(
    int lvl, unsigned* __restrict__ ctr, int nch,
    const float2* __restrict__ uv2, const float* __restrict__ tables,
    const uint32* __restrict__ tbf, uint32* __restrict__ feats,
    int npts, int lane)
{
    const unsigned res = 16u << lvl;
    const float fres = (float)res;
    const unsigned rp1 = res + 1u;
    const bool dense = lvl < 6;               // (res+1)^2 <= T
    const unsigned mask = T_SIZE - 1u;
    const uint32* tb = tbf + (size_t)(lvl - 6) * T_SIZE;      // hashed bf16
    const float2* td = (const float2*)tables + (size_t)lvl * T_SIZE;  // dense f32
    uint32* fp = feats + (size_t)lvl * npts;
    for (;;) {
        unsigned c = 0;
        if (lane == 0) c = atomicAdd(&ctr[lvl], 1u);
        c = (unsigned)__shfl((int)c, 0);
        if (c >= (unsigned)nch) break;
        int base = (int)c * CHPTS;
#pragma unroll
        for (int i = 0; i < CHPTS / 64; ++i) {
            int pt = base + i * 64 + lane;
            if (pt >= npts) continue;
            union { unsigned long long u; float2 f; } pr;
            pr.u = __builtin_nontemporal_load((const unsigned long long*)(uv2 + pt));
            float px = pr.f.x * fres, py = pr.f.y * fres;
            float fx = floorf(px), fy = floorf(py);
            float wx = px - fx, wy = py - fy;
            unsigned cx = (unsigned)fx, cy = (unsigned)fy;
            float w00 = (1.f - wx) * (1.f - wy);
            float w01 = (1.f - wx) * wy;
            float w10 = wx * (1.f - wy);
            float w11 = wx * wy;
            float g0, g1;
            if (dense) {
                unsigned i00 = cx + cy * rp1;
                unsigned i01 = cx + (cy + 1u) * rp1;
                unsigned i10 = i00 + 1u, i11 = i01 + 1u;
                float2 f00 = td[i00], f01 = td[i01], f10 = td[i10], f11 = td[i11];
                g0 = w00 * f00.x + w01 * f01.x + w10 * f10.x + w11 * f11.x;
                g1 = w00 * f00.y + w01 * f01.y + w10 * f10.y + w11 * f11.y;
            } else {
                unsigned hy0 = cy * HASH_Y, hy1 = (cy + 1u) * HASH_Y;
                uint32 e00 = tb[(cx ^ hy0) & mask];
                uint32 e01 = tb[(cx ^ hy1) & mask];
                uint32 e10 = tb[((cx + 1u) ^ hy0) & mask];
                uint32 e11 = tb[((cx + 1u) ^ hy1) & mask];
                g0 = w00 * bflo(e00) + w01 * bflo(e01) + w10 * bflo(e10) + w11 * bflo(e11);
                g1 = w00 * bfhi(e00) + w01 * bfhi(e01) + w10 * bfhi(e10) + w11 * bfhi(e11);
            }
            __builtin_nontemporal_store(pack2(g0, g1), fp + pt);
        }
    }
}

__global__ __launch_bounds__(256, 4)
void encode_lvl(const float2* __restrict__ uv2, const float* __restrict__ tables,
                const uint32* __restrict__ tbf, uint32* __restrict__ feats,
                unsigned* __restrict__ ctr, int npts)
{
    const int lane = threadIdx.x & 63;
    const int nch = (npts + CHPTS - 1) / CHPTS;
    // Real XCD id: s_getreg(HW_REG_XCC_ID=20, offset 0, size 32) -> simm16 =
    // 20 | (31<<11) = 63508. Wave-uniform. Any garbage value still correct
    // (queues + stealing), only locality degrades.
    int xcc = (int)(__builtin_amdgcn_s_getreg(63508) & 7u);
    // Primary: one hashed level (6+xcc); secondary: levels 14,15 on XCD 0,1,
    // dense 0..5 on XCD 2..7.
    run_level(6 + xcc, ctr, nch, uv2, tables, tbf, feats, npts, lane);
    int p1 = (xcc < 2) ? (14 + xcc) : (xcc - 2);
    run_level(p1, ctr, nch, uv2, tables, tbf, feats, npts, lane);
    // Steal whatever remains (hashed first).
    for (int i = 0; i < NLVL; ++i) {
        int l = (i < 10) ? (6 + i) : (i - 10);
        run_level(l, ctr, nch, uv2, tables, tbf, feats, npts, lane);
    }
}

// ---------------- shared MLP LDS staging + body ----------------
// LDS: w1T frag [q][m=128][8] 8192B + w2T padded [m=128][136] 34816B +
// w3T frag [ks][q][m=16][8] 4096B + hbuf [4wv][16][136] 17408B +
// b1s/b2s bf16 512B = 65024B <= 64KB. 2 blocks/CU.
#define MLP_LDS_INIT()                                                            \
    __shared__ __align__(16) unsigned short w1T[32 * 128];                        \
    __shared__ __align__(16) unsigned short w2T[128 * 136];                       \
    __shared__ __align__(16) unsigned short w3T[4 * 4 * 16 * 8];                  \
    __shared__ __align__(16) unsigned short hbuf[4 * 16 * 136];                   \
    __shared__ unsigned short b1s[128], b2s[128];                                 \
    const int tid = threadIdx.x;                                                  \
    for (int idx = tid; idx < 32 * 128; idx += 256) {                             \
        int j_ = idx & 7, t_ = idx >> 3, m_ = t_ & 127, q_ = t_ >> 7;             \
        w1T[idx] = f2bf(w1[(q_ * 8 + j_) * 128 + m_]);                            \
    }                                                                             \
    for (int idx = tid; idx < 128 * 128; idx += 256) {                            \
        int i_ = idx >> 7, o_ = idx & 127;                                        \
        w2T[o_ * 136 + i_] = f2bf(w2[idx]);                                       \
    }                                                                             \
    for (int idx = tid; idx < 2048; idx += 256) {                                 \
        int j_ = idx & 7, t_ = idx >> 3, m_ = t_ & 15;                            \
        int q_ = (t_ >> 4) & 3, ks_ = t_ >> 6;                                    \
        w3T[idx] = (m_ < 3) ? f2bf(w3[(ks_ * 32 + q_ * 8 + j_) * 3 + m_])         \
                            : (unsigned short)0;                                  \
    }                                                                             \
    if (tid < 128) { b1s[tid] = f2bf(b1[tid]); b2s[tid] = f2bf(b2[tid]); }        \
    __syncthreads();                                                              \
    const int lane = tid & 63;                                                    \
    const int wv = tid >> 6;                                                      \
    const int lanelo = lane & 15;                                                 \
    const int quad = lane >> 4;                                                   \
    unsigned short* hp = hbuf + (wv * 16 + lanelo) * 136;

// MLP body: only scalars + LDS/global pointers (no per-thread arrays to spill).
static __device__ __forceinline__ void mlp_body(
    u16x8 xb, int pt, int quad, int lanelo,
    unsigned short* __restrict__ hp,
    const unsigned short* __restrict__ w1T, const unsigned short* __restrict__ w2T,
    const unsigned short* __restrict__ w3T,
    const unsigned short* __restrict__ b1s, const unsigned short* __restrict__ b2s,
    float b3x, float b3y, float b3z, float* __restrict__ out)
{
    f32x4 z = {0.f, 0.f, 0.f, 0.f};
    // layer 1: K=32, 8 MFMAs, A from LDS
    f32x4 d[8];
#pragma unroll
    for (int mt = 0; mt < 8; ++mt) {
        u16x8 aa = *(const u16x8*)(w1T + (quad * 128 + mt * 16 + lanelo) * 8);
        d[mt] = mfma16(aa, xb, z);
    }
#pragma unroll
    for (int mt = 0; mt < 8; ++mt) {
        u16x4 pk;
#pragma unroll
        for (int r = 0; r < 4; ++r) {
            float hv = d[mt][r] + bfu(b1s[mt * 16 + quad * 4 + r]);
            pk[r] = f2bf(fmaxf(hv, 0.f));
        }
        *(u16x4*)(hp + mt * 16 + quad * 4) = pk;
    }
    // layer 2: K=128, 32 MFMAs
    f32x4 e[8];
#pragma unroll
    for (int mt = 0; mt < 8; ++mt) e[mt] = z;
#pragma unroll
    for (int ks = 0; ks < 4; ++ks) {
        u16x8 bb = *(const u16x8*)(hp + ks * 32 + quad * 8);
#pragma unroll
        for (int mt = 0; mt < 8; ++mt) {
            u16x8 aa = *(const u16x8*)(w2T + (mt * 16 + lanelo) * 136 + ks * 32 + quad * 8);
            e[mt] = mfma16(aa, bb, e[mt]);
        }
    }
#pragma unroll
    for (int mt = 0; mt < 8; ++mt) {
        u16x4 pk;
#pragma unroll
        for (int r = 0; r < 4; ++r) {
            float hv = e[mt][r] + bfu(b2s[mt * 16 + quad * 4 + r]);
            pk[r] = f2bf(fmaxf(hv, 0.f));
        }
        *(u16x4*)(hp + mt * 16 + quad * 4) = pk;
    }
    // layer 3: K=128, 4 MFMAs
    f32x4 o3 = z;
#pragma unroll
    for (int ks = 0; ks < 4; ++ks) {
        u16x8 bb = *(const u16x8*)(hp + ks * 32 + quad * 8);
        u16x8 aa = *(const u16x8*)(w3T + ((ks * 4 + quad) * 16 + lanelo) * 8);
        o3 = mfma16(aa, bb, o3);
    }
    if (quad == 0) {
        float* op = out + (size_t)pt * 3;
        op[0] = 1.f / (1.f + expf(-(o3[0] + b3x)));
        op[1] = 1.f / (1.f + expf(-(o3[1] + b3y)));
        op[2] = 1.f / (1.f + expf(-(o3[2] + b3z)));
    }
}

// ---------------- K3: MLP over feature planes ----------------
__global__ __launch_bounds__(256, 2)
void mlp_feats(const uint32* __restrict__ feats,
               const float* __restrict__ w1, const float* __restrict__ b1,
               const float* __restrict__ w2, const float* __restrict__ b2,
               const float* __restrict__ w3, const float* __restrict__ b3,
               float* __restrict__ out, int npts)
{
    MLP_LDS_INIT();
    const float b3x = b3[0], b3y = b3[1], b3z = b3[2];
    const int NT = npts >> 4;
    const int nwaves = gridDim.x * 4;
    for (int tile = blockIdx.x * 4 + wv; tile < NT; tile += nwaves) {
        int pt = (tile << 4) + lanelo;
        u16x8 xb;
#pragma unroll
        for (int i = 0; i < 4; ++i) {
            uint32 u = __builtin_nontemporal_load(
                feats + (size_t)(quad * 4 + i) * npts + pt);
            xb[2 * i]     = (unsigned short)(u & 0xffffu);
            xb[2 * i + 1] = (unsigned short)(u >> 16);
        }
        mlp_body(xb, pt, quad, lanelo, hp, w1T, w2T, w3T, b1s, b2s, b3x, b3y, b3z, out);
    }
}

// ---------------- fallback: fused gather + MLP (no workspace needed) -------
__global__ __launch_bounds__(256, 2)
void fused_fallback(const float* __restrict__ uv, const float* __restrict__ tables,
                    const float* __restrict__ w1, const float* __restrict__ b1,
                    const float* __restrict__ w2, const float* __restrict__ b2,
                    const float* __restrict__ w3, const float* __restrict__ b3,
                    float* __restrict__ out, int npts)
{
    MLP_LDS_INIT();
    const float b3x = b3[0], b3y = b3[1], b3z = b3[2];
    const int NT = npts >> 4;
    const int nwaves = gridDim.x * 4;
    const float2* t2base = (const float2*)tables;
    const float2* uv2 = (const float2*)uv;
    for (int tile = blockIdx.x * 4 + wv; tile < NT; tile += nwaves) {
        int pt = (tile << 4) + lanelo;
        float2 p = uv2[pt];
        u16x8 xb;
#pragma unroll
        for (int i = 0; i < 4; ++i) {
            int lvl = (quad << 2) + i;
            unsigned res = 16u << lvl;
            float px = p.x * (float)res, py = p.y * (float)res;
            float fx = floorf(px), fy = floorf(py);
            float wx = px - fx, wy = py - fy;
            unsigned cx = (unsigned)fx, cy = (unsigned)fy;
            unsigned rp1 = res + 1u;
            unsigned hy0 = cy * HASH_Y, hy1 = (cy + 1u) * HASH_Y;
            const unsigned mask = T_SIZE - 1u;
            bool dense = lvl < 6;
            unsigned i00 = dense ? (cx + cy * rp1)             : ((cx ^ hy0) & mask);
            unsigned i01 = dense ? (cx + (cy + 1u) * rp1)      : ((cx ^ hy1) & mask);
            unsigned i10 = dense ? (cx + 1u + cy * rp1)        : (((cx + 1u) ^ hy0) & mask);
            unsigned i11 = dense ? (cx + 1u + (cy + 1u) * rp1) : (((cx + 1u) ^ hy1) & mask);
            const float2* t2 = t2base + (size_t)lvl * T_SIZE;
            float2 f00 = t2[i00], f01 = t2[i01], f10 = t2[i10], f11 = t2[i11];
            float w00 = (1.f - wx) * (1.f - wy);
            float w01 = (1.f - wx) * wy;
            float w10 = wx * (1.f - wy);
            float w11 = wx * wy;
            float g0 = w00 * f00.x + w01 * f01.x + w10 * f10.x + w11 * f11.x;
            float g1 = w00 * f00.y + w01 * f01.y + w10 * f10.y + w11 * f11.y;
            xb[2 * i]     = f2bf(g0);
            xb[2 * i + 1] = f2bf(g1);
        }
        mlp_body(xb, pt, quad, lanelo, hp, w1T, w2T, w3T, b1s, b2s, b3x, b3y, b3z, out);
    }
}

extern "C" void kernel_launch(void* const* d_in, const int* in_sizes, int n_in,
                              void* d_out, int out_size, void* d_ws, size_t ws_size,
                              hipStream_t stream) {
    const float* uv     = (const float*)d_in[0];
    const float* tables = (const float*)d_in[1];
    const float* w1     = (const float*)d_in[2];
    const float* b1     = (const float*)d_in[3];
    const float* w2     = (const float*)d_in[4];
    const float* b2     = (const float*)d_in[5];
    const float* w3     = (const float*)d_in[6];
    const float* b3     = (const float*)d_in[7];
    float* out = (float*)d_out;
    int npts = in_sizes[0] / 2;

    const size_t TB_BYTES  = (size_t)10 * T_SIZE * 4;            // 40 MiB bf16 hashed tables
    const size_t FT_BYTES  = (size_t)NLVL * (size_t)npts * 4;    // 64 MiB feature planes
    const size_t CTR_BYTES = 64 * sizeof(unsigned);
    if (ws_size < TB_BYTES + FT_BYTES + CTR_BYTES) {
        hipLaunchKernelGGL(fused_fallback, dim3(1024), dim3(256), 0, stream,
                           uv, tables, w1, b1, w2, b2, w3, b3, out, npts);
        return;
    }
    uint32*   tbf   = (uint32*)d_ws;
    uint32*   feats = (uint32*)((char*)d_ws + TB_BYTES);
    unsigned* ctr   = (unsigned*)((char*)d_ws + TB_BYTES + FT_BYTES);

    hipMemsetAsync(ctr, 0, CTR_BYTES, stream);
    // K1: convert hashed-level tables (levels 6..15): 10 * 2^20 * 2 floats.
    int n4 = (10 * (int)T_SIZE * 2) / 4;
    hipLaunchKernelGGL(cvt_tables, dim3(2048), dim3(256), 0, stream,
                       (const float4*)(tables + (size_t)6 * T_SIZE * 2),
                       (uint2*)tbf, n4);
    // K2: queue-driven encode (1024 blocks, ~128/XCD sweep one level at a time).
    hipLaunchKernelGGL(encode_lvl, dim3(1024), dim3(256), 0, stream,
                       (const float2*)uv, tables, tbf, feats, ctr, npts);
    // K3: MFMA MLP, 512 blocks = 2/CU (LDS-bound), 32 tiles/wave.
    hipLaunchKernelGGL(mlp_feats, dim3(512), dim3(256), 0, stream,
                       feats, w1, b1, w2, b2, w3, b3, out, npts);
}